// Round 1
// 191.826 us; speedup vs baseline: 1.1059x; 1.1059x over previous
//
#include <hip/hip_runtime.h>

// out = L@(X@W1 + X^2@W2) + X@W1 + b1 + b2
// Y (bf16, ws) = X@W1 + X^2@W2 ; Z = X@W1 + b1 + b2 (node_transform -> out).
// Fixed-capacity 128-row buckets (CAP=2048, +13 sigma above mean 1536):
//   cursor_init -> bin_scatter (LDS chunk-sort, coalesced runs, overflow
//   append if a bucket ever exceeds CAP) -> bucket_gather_rows (2 blocks
//   per bucket, ROW halves, all 64 features, dword bf16x2 gather loads,
//   in-LDS counting sort storing sorted edges directly) -> overflow_scatter
//   (empty in practice). No global output atomics.

#define ROWS_PER_BUCKET 128
#define ROW_SHIFT 7
#define NBUCK_PAD 784        // 196*4, covers nbuck=782
#define SCAN_T 196
#define CAP 2048             // per-bucket fixed capacity
#define CHUNK 4096           // edges per bin_scatter block
#define MAXB 2048            // max bucket-chunk held in LDS by gather
#define COL_BITS 17
#define COL_MASK 0x1FFFF
#define OVF_CAP 65536

__device__ __forceinline__ unsigned short f2bf(float x) {
    unsigned u = __float_as_uint(x);
    unsigned r = (u + 0x7FFFu + ((u >> 16) & 1u)) >> 16;   // RNE
    return (unsigned short)r;
}
__device__ __forceinline__ float bf2f(unsigned short h) {
    return __uint_as_float(((unsigned)h) << 16);
}

__global__ __launch_bounds__(256) void node_transform(
    const float* __restrict__ X, const float* __restrict__ W1,
    const float* __restrict__ b1, const float* __restrict__ W2,
    const float* __restrict__ b2, unsigned short* __restrict__ Yb,
    float* __restrict__ Z, int n_nodes)
{
    __shared__ float W1s[64 * 64];
    __shared__ float W2s[64 * 64];
    __shared__ float xs[128][65];
    __shared__ float bs[64];

    const int tid = threadIdx.x;
    const int base = blockIdx.x * 128;

    {
        const float4* w1v = (const float4*)W1;
        const float4* w2v = (const float4*)W2;
        float4* s1 = (float4*)W1s;
        float4* s2 = (float4*)W2s;
#pragma unroll
        for (int i = 0; i < 4; ++i) {
            s1[tid + 256 * i] = w1v[tid + 256 * i];
            s2[tid + 256 * i] = w2v[tid + 256 * i];
        }
    }
    if (tid < 64) bs[tid] = b1[tid] + b2[tid];

    {
#pragma unroll
        for (int i = 0; i < 8; ++i) {
            int idx = (tid + 256 * i) * 4;
            int r = idx >> 6, c = idx & 63;
            if (base + r < n_nodes) {
                float4 v = *(const float4*)(X + (size_t)base * 64 + idx);
                xs[r][c + 0] = v.x; xs[r][c + 1] = v.y;
                xs[r][c + 2] = v.z; xs[r][c + 3] = v.w;
            }
        }
    }
    __syncthreads();

    const int tx = tid & 7;
    const int ty = tid >> 3;

    float acc1[4][8] = {};
    float acc2[4][8] = {};

#pragma unroll 2
    for (int k = 0; k < 64; ++k) {
        float4 wa0 = *(const float4*)(W1s + k * 64 + tx * 8);
        float4 wa1 = *(const float4*)(W1s + k * 64 + tx * 8 + 4);
        float4 wb0 = *(const float4*)(W2s + k * 64 + tx * 8);
        float4 wb1 = *(const float4*)(W2s + k * 64 + tx * 8 + 4);
#pragma unroll
        for (int i = 0; i < 4; ++i) {
            float xv = xs[ty * 4 + i][k];
            float xq = xv * xv;
            acc1[i][0] = fmaf(xv, wa0.x, acc1[i][0]);
            acc1[i][1] = fmaf(xv, wa0.y, acc1[i][1]);
            acc1[i][2] = fmaf(xv, wa0.z, acc1[i][2]);
            acc1[i][3] = fmaf(xv, wa0.w, acc1[i][3]);
            acc1[i][4] = fmaf(xv, wa1.x, acc1[i][4]);
            acc1[i][5] = fmaf(xv, wa1.y, acc1[i][5]);
            acc1[i][6] = fmaf(xv, wa1.z, acc1[i][6]);
            acc1[i][7] = fmaf(xv, wa1.w, acc1[i][7]);
            acc2[i][0] = fmaf(xq, wb0.x, acc2[i][0]);
            acc2[i][1] = fmaf(xq, wb0.y, acc2[i][1]);
            acc2[i][2] = fmaf(xq, wb0.z, acc2[i][2]);
            acc2[i][3] = fmaf(xq, wb0.w, acc2[i][3]);
            acc2[i][4] = fmaf(xq, wb1.x, acc2[i][4]);
            acc2[i][5] = fmaf(xq, wb1.y, acc2[i][5]);
            acc2[i][6] = fmaf(xq, wb1.z, acc2[i][6]);
            acc2[i][7] = fmaf(xq, wb1.w, acc2[i][7]);
        }
    }

    float bv[8];
#pragma unroll
    for (int j = 0; j < 8; ++j) bv[j] = bs[tx * 8 + j];

#pragma unroll
    for (int i = 0; i < 4; ++i) {
        int node = base + ty * 4 + i;
        if (node < n_nodes) {
            float z[8];
            unsigned pk[4];
#pragma unroll
            for (int j = 0; j < 4; ++j) {
                float ylo = acc1[i][2 * j]     + acc2[i][2 * j];
                float yhi = acc1[i][2 * j + 1] + acc2[i][2 * j + 1];
                pk[j] = (unsigned)f2bf(ylo) | ((unsigned)f2bf(yhi) << 16);
            }
#pragma unroll
            for (int j = 0; j < 8; ++j) z[j] = acc1[i][j] + bv[j];
            unsigned short* yp = Yb + (size_t)node * 64 + tx * 8;
            float* zp = Z + (size_t)node * 64 + tx * 8;
            *(uint4*)(yp) = make_uint4(pk[0], pk[1], pk[2], pk[3]);
            *(float4*)(zp)     = make_float4(z[0], z[1], z[2], z[3]);
            *(float4*)(zp + 4) = make_float4(z[4], z[5], z[6], z[7]);
        }
    }
}

// ---------------- fixed-capacity bucket build ----------------

__global__ __launch_bounds__(256) void cursor_init(
    int* __restrict__ gcursor, int* __restrict__ ovf_count, int nbp) {
    int i = blockIdx.x * 256 + threadIdx.x;
    if (i < nbp) gcursor[i] = i * CAP;
    if (i == 0) *ovf_count = 0;
}

// LDS-staged binned scatter with fixed-capacity buckets + overflow append.
__global__ __launch_bounds__(256) void bin_scatter(
    const int* __restrict__ rows, const int* __restrict__ cols,
    const float* __restrict__ vals, int* __restrict__ gcursor,
    int2* __restrict__ packed, int* __restrict__ ovf_count,
    int4* __restrict__ ovf, int n_edges) {
    __shared__ int lcount[NBUCK_PAD];
    __shared__ int lstart[NBUCK_PAD];
    __shared__ int lcursor[NBUCK_PAD];
    __shared__ int gbase[NBUCK_PAD];
    __shared__ int sx[CHUNK];
    __shared__ int sy[CHUNK];
    __shared__ unsigned short sbk[CHUNK];

    int tid = threadIdx.x;
    int eb0 = blockIdx.x * CHUNK;
    int cnt = min(CHUNK, n_edges - eb0);

    for (int k = tid; k < NBUCK_PAD; k += 256) lcount[k] = 0;
    __syncthreads();

    for (int i = tid; i < cnt; i += 256)
        atomicAdd(&lcount[rows[eb0 + i] >> ROW_SHIFT], 1);
    __syncthreads();

    // exclusive scan of lcount[0..NBUCK_PAD): thread t<SCAN_T owns 4t..4t+3
    int c0 = 0, c1 = 0, c2 = 0, c3 = 0, psum = 0;
    if (tid < SCAN_T) {
        c0 = lcount[tid * 4 + 0]; c1 = lcount[tid * 4 + 1];
        c2 = lcount[tid * 4 + 2]; c3 = lcount[tid * 4 + 3];
        psum = c0 + c1 + c2 + c3;
    }
    sx[tid] = psum;
    __syncthreads();
#pragma unroll
    for (int o = 1; o < 256; o <<= 1) {
        int t = (tid >= o) ? sx[tid - o] : 0;
        __syncthreads();
        sx[tid] += t;
        __syncthreads();
    }
    int base0 = sx[tid] - psum;
    __syncthreads();
    if (tid < SCAN_T) {
        lstart[tid * 4 + 0] = base0;
        lstart[tid * 4 + 1] = base0 + c0;
        lstart[tid * 4 + 2] = base0 + c0 + c1;
        lstart[tid * 4 + 3] = base0 + c0 + c1 + c2;
    }
    __syncthreads();

    for (int k = tid; k < NBUCK_PAD; k += 256) {
        lcursor[k] = lstart[k];
        if (lcount[k] > 0) gbase[k] = atomicAdd(&gcursor[k], lcount[k]);
    }
    __syncthreads();

    for (int i = tid; i < cnt; i += 256) {
        int r = rows[eb0 + i];
        int b = r >> ROW_SHIFT;
        int p = atomicAdd(&lcursor[b], 1);
        sx[p] = ((r & (ROWS_PER_BUCKET - 1)) << COL_BITS) | cols[eb0 + i];
        sy[p] = __float_as_int(vals[eb0 + i]);
        sbk[p] = (unsigned short)b;
    }
    __syncthreads();

    for (int i = tid; i < cnt; i += 256) {
        int b = sbk[i];
        int dest = gbase[b] + (i - lstart[b]);
        if (dest < (b + 1) * CAP) {
            packed[dest] = make_int2(sx[i], sy[i]);
        } else {
            int p = atomicAdd(ovf_count, 1);
            if (p < OVF_CAP)
                ovf[p] = make_int4(b * ROWS_PER_BUCKET + (sx[i] >> COL_BITS),
                                   sx[i] & COL_MASK, sy[i], 0);
        }
    }
}

// 2 blocks per bucket, split by ROW halves (64 rows each, all 64 features).
// In-LDS counting sort by local row stores sorted int2 edges directly
// (packed chunk re-read from L2 in pass 2 -- no dsti indirection). Gather
// loads Yb as dwords (bf16x2): one lane covers a feature PAIR, a half-wave
// reads a full 128B Y row per load instruction.
__global__ __launch_bounds__(256) void bucket_gather_rows(
    const int* __restrict__ gcursor, const int2* __restrict__ packed,
    const unsigned short* __restrict__ Yb, float* __restrict__ out,
    int n_nodes) {
    __shared__ int2 sxy[MAXB];                     // 16 KB, sorted by row
    __shared__ int hist[ROWS_PER_BUCKET];
    __shared__ int chs[ROWS_PER_BUCKET];
    __shared__ int chc[ROWS_PER_BUCKET];

    int tid = threadIdx.x;
    int bucket = blockIdx.x >> 1;
    int rhalf = (blockIdx.x & 1) * 64;   // which 64-row half this block owns
    int fpair = tid & 31;                // features 2*fpair, 2*fpair+1
    int rowlane = tid >> 5;              // 0..7
    int s = bucket * CAP;
    int e = min(gcursor[bucket], s + CAP);
    int row0 = bucket * ROWS_PER_BUCKET;
    const unsigned* __restrict__ Y32 = (const unsigned*)Yb;

    for (int cb = s; cb < e; cb += MAXB) {
        int cnt = min(MAXB, e - cb);

        if (tid < ROWS_PER_BUCKET) hist[tid] = 0;
        __syncthreads();

        // pass 1: histogram of local rows
        for (int i = tid; i < cnt; i += 256)
            atomicAdd(&hist[packed[cb + i].x >> COL_BITS], 1);
        __syncthreads();

        if (tid < ROWS_PER_BUCKET) chs[tid] = hist[tid];
        __syncthreads();
#pragma unroll
        for (int o = 1; o < ROWS_PER_BUCKET; o <<= 1) {
            int t = 0;
            if (tid < ROWS_PER_BUCKET && tid >= o) t = chs[tid - o];
            __syncthreads();
            if (tid < ROWS_PER_BUCKET) chs[tid] += t;
            __syncthreads();
        }
        if (tid < ROWS_PER_BUCKET) {
            int excl = chs[tid] - hist[tid];
            chs[tid] = excl;
            chc[tid] = excl;
        }
        __syncthreads();

        // pass 2: scatter sorted edges directly into LDS (packed is L2-hot)
        for (int i = tid; i < cnt; i += 256) {
            int2 a = packed[cb + i];
            int p = atomicAdd(&chc[a.x >> COL_BITS], 1);
            sxy[p] = a;
        }
        __syncthreads();

        // gather: 8 row-groups x 8 rows, 32 lanes per row, 2 features/lane
        for (int rr = 0; rr < 8; ++rr) {
            int r = rhalf + rowlane * 8 + rr;
            int rc = hist[r];
            int node = row0 + r;
            if (rc == 0 || node >= n_nodes) continue;
            int rs = chs[r];
            float a0 = 0.f, a1 = 0.f;
            int j = 0;
            for (; j + 8 <= rc; j += 8) {
                int2 e0 = sxy[rs + j + 0], e1 = sxy[rs + j + 1];
                int2 e2 = sxy[rs + j + 2], e3 = sxy[rs + j + 3];
                int2 e4 = sxy[rs + j + 4], e5 = sxy[rs + j + 5];
                int2 e6 = sxy[rs + j + 6], e7 = sxy[rs + j + 7];
                unsigned u0 = Y32[(size_t)(e0.x & COL_MASK) * 32 + fpair];
                unsigned u1 = Y32[(size_t)(e1.x & COL_MASK) * 32 + fpair];
                unsigned u2 = Y32[(size_t)(e2.x & COL_MASK) * 32 + fpair];
                unsigned u3 = Y32[(size_t)(e3.x & COL_MASK) * 32 + fpair];
                unsigned u4 = Y32[(size_t)(e4.x & COL_MASK) * 32 + fpair];
                unsigned u5 = Y32[(size_t)(e5.x & COL_MASK) * 32 + fpair];
                unsigned u6 = Y32[(size_t)(e6.x & COL_MASK) * 32 + fpair];
                unsigned u7 = Y32[(size_t)(e7.x & COL_MASK) * 32 + fpair];
                float v0 = __int_as_float(e0.y), v1 = __int_as_float(e1.y);
                float v2 = __int_as_float(e2.y), v3 = __int_as_float(e3.y);
                float v4 = __int_as_float(e4.y), v5 = __int_as_float(e5.y);
                float v6 = __int_as_float(e6.y), v7 = __int_as_float(e7.y);
                a0 = fmaf(v0, __uint_as_float(u0 << 16), a0);
                a1 = fmaf(v0, __uint_as_float(u0 & 0xFFFF0000u), a1);
                a0 = fmaf(v1, __uint_as_float(u1 << 16), a0);
                a1 = fmaf(v1, __uint_as_float(u1 & 0xFFFF0000u), a1);
                a0 = fmaf(v2, __uint_as_float(u2 << 16), a0);
                a1 = fmaf(v2, __uint_as_float(u2 & 0xFFFF0000u), a1);
                a0 = fmaf(v3, __uint_as_float(u3 << 16), a0);
                a1 = fmaf(v3, __uint_as_float(u3 & 0xFFFF0000u), a1);
                a0 = fmaf(v4, __uint_as_float(u4 << 16), a0);
                a1 = fmaf(v4, __uint_as_float(u4 & 0xFFFF0000u), a1);
                a0 = fmaf(v5, __uint_as_float(u5 << 16), a0);
                a1 = fmaf(v5, __uint_as_float(u5 & 0xFFFF0000u), a1);
                a0 = fmaf(v6, __uint_as_float(u6 << 16), a0);
                a1 = fmaf(v6, __uint_as_float(u6 & 0xFFFF0000u), a1);
                a0 = fmaf(v7, __uint_as_float(u7 << 16), a0);
                a1 = fmaf(v7, __uint_as_float(u7 & 0xFFFF0000u), a1);
            }
            for (; j + 2 <= rc; j += 2) {
                int2 e0 = sxy[rs + j + 0], e1 = sxy[rs + j + 1];
                unsigned u0 = Y32[(size_t)(e0.x & COL_MASK) * 32 + fpair];
                unsigned u1 = Y32[(size_t)(e1.x & COL_MASK) * 32 + fpair];
                float v0 = __int_as_float(e0.y), v1 = __int_as_float(e1.y);
                a0 = fmaf(v0, __uint_as_float(u0 << 16), a0);
                a1 = fmaf(v0, __uint_as_float(u0 & 0xFFFF0000u), a1);
                a0 = fmaf(v1, __uint_as_float(u1 << 16), a0);
                a1 = fmaf(v1, __uint_as_float(u1 & 0xFFFF0000u), a1);
            }
            if (j < rc) {
                int2 e0 = sxy[rs + j];
                unsigned u0 = Y32[(size_t)(e0.x & COL_MASK) * 32 + fpair];
                float v0 = __int_as_float(e0.y);
                a0 = fmaf(v0, __uint_as_float(u0 << 16), a0);
                a1 = fmaf(v0, __uint_as_float(u0 & 0xFFFF0000u), a1);
            }
            float2* op = (float2*)(out + (size_t)node * 64 + fpair * 2);
            float2 o = *op;
            o.x += a0; o.y += a1;
            *op = o;                                 // out holds Z
        }
        __syncthreads();
    }
}

// drains the (normally empty) overflow list with global atomics
__global__ __launch_bounds__(256) void overflow_scatter(
    const int* __restrict__ ovf_count, const int4* __restrict__ ovf,
    const unsigned short* __restrict__ Yb, float* __restrict__ out) {
    int cnt = min(*ovf_count, OVF_CAP);
    long long total = (long long)cnt * 64;
    for (long long i = blockIdx.x * 256 + threadIdx.x; i < total;
         i += (long long)gridDim.x * 256) {
        int e = (int)(i >> 6), f = (int)(i & 63);
        int4 a = ovf[e];
        atomicAdd(&out[(size_t)a.x * 64 + f],
                  __int_as_float(a.z) * bf2f(Yb[(size_t)a.y * 64 + f]));
    }
}

// ---------------- fallback (atomic path) ----------------

__global__ __launch_bounds__(256) void edge_scatter(
    const int* __restrict__ rows, const int* __restrict__ cols,
    const float* __restrict__ vals, const unsigned short* __restrict__ Yb,
    float* __restrict__ out, int n_edges)
{
    int t = blockIdx.x * 256 + threadIdx.x;
    int e = t >> 4;
    int f = (t & 15) << 2;
    if (e >= n_edges) return;
    int r = rows[e];
    int c = cols[e];
    float v = vals[e];
    const unsigned short* y = Yb + (size_t)c * 64 + f;
    float* o = out + (size_t)r * 64 + f;
    atomicAdd(o + 0, v * bf2f(y[0]));
    atomicAdd(o + 1, v * bf2f(y[1]));
    atomicAdd(o + 2, v * bf2f(y[2]));
    atomicAdd(o + 3, v * bf2f(y[3]));
}

extern "C" void kernel_launch(void* const* d_in, const int* in_sizes, int n_in,
                              void* d_out, int out_size, void* d_ws, size_t ws_size,
                              hipStream_t stream) {
    const int*   rows = (const int*)d_in[0];
    const int*   cols = (const int*)d_in[1];
    const float* vals = (const float*)d_in[2];
    const float* X    = (const float*)d_in[3];
    const float* W1   = (const float*)d_in[4];
    const float* b1   = (const float*)d_in[5];
    const float* W2   = (const float*)d_in[6];
    const float* b2   = (const float*)d_in[7];
    float* out = (float*)d_out;

    const int n_edges = in_sizes[0];
    const int n_nodes = in_sizes[3] / 64;
    const int nbuck = (n_nodes + ROWS_PER_BUCKET - 1) / ROWS_PER_BUCKET;

    char* ws = (char*)d_ws;
    size_t o_Yb     = 0;                                    // bf16 Y
    size_t o_packed = o_Yb + (size_t)n_nodes * 64 * 2;      // 16B-aligned (n*128)
    size_t o_ovf    = o_packed + (size_t)NBUCK_PAD * CAP * 8;
    size_t o_gcurs  = o_ovf + (size_t)OVF_CAP * 16;
    size_t o_ovfcnt = o_gcurs + NBUCK_PAD * 4;
    size_t need     = o_ovfcnt + 16;

    unsigned short* Yb = (unsigned short*)(ws + o_Yb);

    int nblocks = (n_nodes + 127) / 128;
    node_transform<<<nblocks, 256, 0, stream>>>(X, W1, b1, W2, b2, Yb, out, n_nodes);

    if (ws_size >= need && nbuck <= NBUCK_PAD && n_nodes <= (1 << COL_BITS)) {
        int2* packed  = (int2*)(ws + o_packed);
        int4* ovf     = (int4*)(ws + o_ovf);
        int*  gcursor = (int*)(ws + o_gcurs);
        int*  ovfcnt  = (int*)(ws + o_ovfcnt);

        int eb = (n_edges + CHUNK - 1) / CHUNK;

        cursor_init<<<(NBUCK_PAD + 255) / 256, 256, 0, stream>>>(gcursor, ovfcnt, NBUCK_PAD);
        bin_scatter<<<eb, 256, 0, stream>>>(rows, cols, vals, gcursor, packed,
                                            ovfcnt, ovf, n_edges);
        bucket_gather_rows<<<nbuck * 2, 256, 0, stream>>>(gcursor, packed, Yb, out, n_nodes);
        overflow_scatter<<<128, 256, 0, stream>>>(ovfcnt, ovf, Yb, out);
    } else {
        long long threads = (long long)n_edges * 16;
        int eblocks = (int)((threads + 255) / 256);
        edge_scatter<<<eblocks, 256, 0, stream>>>(rows, cols, vals, Yb, out, n_edges);
    }
}

// Round 2
// 172.351 us; speedup vs baseline: 1.2309x; 1.1130x over previous
//
#include <hip/hip_runtime.h>

// out = L@(X@W1 + X^2@W2) + X@W1 + b1 + b2
// Y (bf16, ws) = X@W1 + X^2@W2 ; Z = X@W1 + b1 + b2 (node_transform -> out).
// node_transform is MFMA-based (16x16x32 bf16, zero LDS): per 4-wave block,
// each wave owns 32 rows; W1/W2 frags live in registers (L2-hot loads),
// X read coalesced from global, X^2 formed in-register.
// SpMM path: fixed-capacity 128-row buckets (CAP=2048):
//   cursor_init -> bin_scatter (LDS chunk-sort) -> bucket_gather_rows
//   (2 blocks/bucket row halves, dword bf16x2 gathers, in-LDS counting
//   sort) -> overflow_scatter (empty in practice). No global out atomics.

#define ROWS_PER_BUCKET 128
#define ROW_SHIFT 7
#define NBUCK_PAD 784        // 196*4, covers nbuck=782
#define SCAN_T 196
#define CAP 2048             // per-bucket fixed capacity
#define CHUNK 4096           // edges per bin_scatter block
#define MAXB 2048            // max bucket-chunk held in LDS by gather
#define COL_BITS 17
#define COL_MASK 0x1FFFF
#define OVF_CAP 65536

typedef __attribute__((ext_vector_type(8))) short bf16x8;
typedef __attribute__((ext_vector_type(4))) float f32x4;

__device__ __forceinline__ unsigned short f2bf(float x) {
    unsigned u = __float_as_uint(x);
    unsigned r = (u + 0x7FFFu + ((u >> 16) & 1u)) >> 16;   // RNE
    return (unsigned short)r;
}
__device__ __forceinline__ float bf2f(unsigned short h) {
    return __uint_as_float(((unsigned)h) << 16);
}

// MFMA node transform: block = 256 threads = 4 waves, 128 rows/block.
// Wave w: rows base+w*32 .. +31. Frags: A row = lane&15, k = 8*(lane>>4)+j;
// B col = lane&15, same k; D row = 4*(lane>>4)+i, col = lane&15.
__global__ __launch_bounds__(256) void node_transform(
    const float* __restrict__ X, const float* __restrict__ W1,
    const float* __restrict__ b1, const float* __restrict__ W2,
    const float* __restrict__ b2, unsigned short* __restrict__ Yb,
    float* __restrict__ Z, int n_nodes)
{
    const int tid = threadIdx.x;
    const int lane = tid & 63;
    const int wave = tid >> 6;          // 0..3
    const int lg = lane >> 4;           // 0..3
    const int lr = lane & 15;

    const int base = blockIdx.x * 128 + wave * 32;

    // ---- B fragments in registers: [mat][ks][cf] ----
    bf16x8 bw1[2][4];
    bf16x8 bw2[2][4];
#pragma unroll
    for (int ks = 0; ks < 2; ++ks) {
#pragma unroll
        for (int cf = 0; cf < 4; ++cf) {
            const int col = cf * 16 + lr;
            const int k0 = ks * 32 + lg * 8;
            bf16x8 t1, t2;
#pragma unroll
            for (int j = 0; j < 8; ++j) {
                t1[j] = (short)f2bf(W1[(k0 + j) * 64 + col]);
                t2[j] = (short)f2bf(W2[(k0 + j) * 64 + col]);
            }
            bw1[ks][cf] = t1;
            bw2[ks][cf] = t2;
        }
    }

    f32x4 acc1[2][4];
    f32x4 acc2[2][4];
#pragma unroll
    for (int rf = 0; rf < 2; ++rf)
#pragma unroll
        for (int cf = 0; cf < 4; ++cf) {
            acc1[rf][cf] = (f32x4){0.f, 0.f, 0.f, 0.f};
            acc2[rf][cf] = (f32x4){0.f, 0.f, 0.f, 0.f};
        }

    // ---- main: load A (X rows, coalesced 32B/lane), square, MFMA ----
#pragma unroll
    for (int rf = 0; rf < 2; ++rf) {
        const int row = base + rf * 16 + lr;
        const bool rok = row < n_nodes;
        const float* xp = X + (size_t)row * 64 + lg * 8;
#pragma unroll
        for (int ks = 0; ks < 2; ++ks) {
            float xv[8];
            if (rok) {
                float4 v0 = *(const float4*)(xp + ks * 32);
                float4 v1 = *(const float4*)(xp + ks * 32 + 4);
                xv[0] = v0.x; xv[1] = v0.y; xv[2] = v0.z; xv[3] = v0.w;
                xv[4] = v1.x; xv[5] = v1.y; xv[6] = v1.z; xv[7] = v1.w;
            } else {
#pragma unroll
                for (int j = 0; j < 8; ++j) xv[j] = 0.f;
            }
            bf16x8 a, q;
#pragma unroll
            for (int j = 0; j < 8; ++j) {
                a[j] = (short)f2bf(xv[j]);
                float s = xv[j] * xv[j];
                q[j] = (short)f2bf(s);
            }
#pragma unroll
            for (int cf = 0; cf < 4; ++cf) {
                acc1[rf][cf] = __builtin_amdgcn_mfma_f32_16x16x32_bf16(
                    a, bw1[ks][cf], acc1[rf][cf], 0, 0, 0);
                acc2[rf][cf] = __builtin_amdgcn_mfma_f32_16x16x32_bf16(
                    q, bw2[ks][cf], acc2[rf][cf], 0, 0, 0);
            }
        }
    }

    // ---- epilogue ----
    float bsv[4];
#pragma unroll
    for (int cf = 0; cf < 4; ++cf)
        bsv[cf] = b1[cf * 16 + lr] + b2[cf * 16 + lr];

#pragma unroll
    for (int rf = 0; rf < 2; ++rf) {
#pragma unroll
        for (int i = 0; i < 4; ++i) {
            const int row = base + rf * 16 + lg * 4 + i;
            if (row < n_nodes) {
#pragma unroll
                for (int cf = 0; cf < 4; ++cf) {
                    const float v1 = acc1[rf][cf][i];
                    const float y = v1 + acc2[rf][cf][i];
                    const float z = v1 + bsv[cf];
                    Yb[(size_t)row * 64 + cf * 16 + lr] = f2bf(y);
                    Z[(size_t)row * 64 + cf * 16 + lr] = z;
                }
            }
        }
    }
}

// ---------------- fixed-capacity bucket build ----------------

__global__ __launch_bounds__(256) void cursor_init(
    int* __restrict__ gcursor, int* __restrict__ ovf_count, int nbp) {
    int i = blockIdx.x * 256 + threadIdx.x;
    if (i < nbp) gcursor[i] = i * CAP;
    if (i == 0) *ovf_count = 0;
}

// LDS-staged binned scatter with fixed-capacity buckets + overflow append.
__global__ __launch_bounds__(256) void bin_scatter(
    const int* __restrict__ rows, const int* __restrict__ cols,
    const float* __restrict__ vals, int* __restrict__ gcursor,
    int2* __restrict__ packed, int* __restrict__ ovf_count,
    int4* __restrict__ ovf, int n_edges) {
    __shared__ int lcount[NBUCK_PAD];
    __shared__ int lstart[NBUCK_PAD];
    __shared__ int lcursor[NBUCK_PAD];
    __shared__ int gbase[NBUCK_PAD];
    __shared__ int sx[CHUNK];
    __shared__ int sy[CHUNK];
    __shared__ unsigned short sbk[CHUNK];

    int tid = threadIdx.x;
    int eb0 = blockIdx.x * CHUNK;
    int cnt = min(CHUNK, n_edges - eb0);

    for (int k = tid; k < NBUCK_PAD; k += 256) lcount[k] = 0;
    __syncthreads();

    for (int i = tid; i < cnt; i += 256)
        atomicAdd(&lcount[rows[eb0 + i] >> ROW_SHIFT], 1);
    __syncthreads();

    // exclusive scan of lcount[0..NBUCK_PAD): thread t<SCAN_T owns 4t..4t+3
    int c0 = 0, c1 = 0, c2 = 0, c3 = 0, psum = 0;
    if (tid < SCAN_T) {
        c0 = lcount[tid * 4 + 0]; c1 = lcount[tid * 4 + 1];
        c2 = lcount[tid * 4 + 2]; c3 = lcount[tid * 4 + 3];
        psum = c0 + c1 + c2 + c3;
    }
    sx[tid] = psum;
    __syncthreads();
#pragma unroll
    for (int o = 1; o < 256; o <<= 1) {
        int t = (tid >= o) ? sx[tid - o] : 0;
        __syncthreads();
        sx[tid] += t;
        __syncthreads();
    }
    int base0 = sx[tid] - psum;
    __syncthreads();
    if (tid < SCAN_T) {
        lstart[tid * 4 + 0] = base0;
        lstart[tid * 4 + 1] = base0 + c0;
        lstart[tid * 4 + 2] = base0 + c0 + c1;
        lstart[tid * 4 + 3] = base0 + c0 + c1 + c2;
    }
    __syncthreads();

    for (int k = tid; k < NBUCK_PAD; k += 256) {
        lcursor[k] = lstart[k];
        if (lcount[k] > 0) gbase[k] = atomicAdd(&gcursor[k], lcount[k]);
    }
    __syncthreads();

    for (int i = tid; i < cnt; i += 256) {
        int r = rows[eb0 + i];
        int b = r >> ROW_SHIFT;
        int p = atomicAdd(&lcursor[b], 1);
        sx[p] = ((r & (ROWS_PER_BUCKET - 1)) << COL_BITS) | cols[eb0 + i];
        sy[p] = __float_as_int(vals[eb0 + i]);
        sbk[p] = (unsigned short)b;
    }
    __syncthreads();

    for (int i = tid; i < cnt; i += 256) {
        int b = sbk[i];
        int dest = gbase[b] + (i - lstart[b]);
        if (dest < (b + 1) * CAP) {
            packed[dest] = make_int2(sx[i], sy[i]);
        } else {
            int p = atomicAdd(ovf_count, 1);
            if (p < OVF_CAP)
                ovf[p] = make_int4(b * ROWS_PER_BUCKET + (sx[i] >> COL_BITS),
                                   sx[i] & COL_MASK, sy[i], 0);
        }
    }
}

// 2 blocks per bucket, split by ROW halves (64 rows each, all 64 features).
// In-LDS counting sort by local row stores sorted int2 edges directly
// (packed chunk re-read from L2 in pass 2 -- no dsti indirection). Gather
// loads Yb as dwords (bf16x2): one lane covers a feature PAIR, a half-wave
// reads a full 128B Y row per load instruction.
__global__ __launch_bounds__(256) void bucket_gather_rows(
    const int* __restrict__ gcursor, const int2* __restrict__ packed,
    const unsigned short* __restrict__ Yb, float* __restrict__ out,
    int n_nodes) {
    __shared__ int2 sxy[MAXB];                     // 16 KB, sorted by row
    __shared__ int hist[ROWS_PER_BUCKET];
    __shared__ int chs[ROWS_PER_BUCKET];
    __shared__ int chc[ROWS_PER_BUCKET];

    int tid = threadIdx.x;
    int bucket = blockIdx.x >> 1;
    int rhalf = (blockIdx.x & 1) * 64;   // which 64-row half this block owns
    int fpair = tid & 31;                // features 2*fpair, 2*fpair+1
    int rowlane = tid >> 5;              // 0..7
    int s = bucket * CAP;
    int e = min(gcursor[bucket], s + CAP);
    int row0 = bucket * ROWS_PER_BUCKET;
    const unsigned* __restrict__ Y32 = (const unsigned*)Yb;

    for (int cb = s; cb < e; cb += MAXB) {
        int cnt = min(MAXB, e - cb);

        if (tid < ROWS_PER_BUCKET) hist[tid] = 0;
        __syncthreads();

        // pass 1: histogram of local rows
        for (int i = tid; i < cnt; i += 256)
            atomicAdd(&hist[packed[cb + i].x >> COL_BITS], 1);
        __syncthreads();

        if (tid < ROWS_PER_BUCKET) chs[tid] = hist[tid];
        __syncthreads();
#pragma unroll
        for (int o = 1; o < ROWS_PER_BUCKET; o <<= 1) {
            int t = 0;
            if (tid < ROWS_PER_BUCKET && tid >= o) t = chs[tid - o];
            __syncthreads();
            if (tid < ROWS_PER_BUCKET) chs[tid] += t;
            __syncthreads();
        }
        if (tid < ROWS_PER_BUCKET) {
            int excl = chs[tid] - hist[tid];
            chs[tid] = excl;
            chc[tid] = excl;
        }
        __syncthreads();

        // pass 2: scatter sorted edges directly into LDS (packed is L2-hot)
        for (int i = tid; i < cnt; i += 256) {
            int2 a = packed[cb + i];
            int p = atomicAdd(&chc[a.x >> COL_BITS], 1);
            sxy[p] = a;
        }
        __syncthreads();

        // gather: 8 row-groups x 8 rows, 32 lanes per row, 2 features/lane
        for (int rr = 0; rr < 8; ++rr) {
            int r = rhalf + rowlane * 8 + rr;
            int rc = hist[r];
            int node = row0 + r;
            if (rc == 0 || node >= n_nodes) continue;
            int rs = chs[r];
            float a0 = 0.f, a1 = 0.f;
            int j = 0;
            for (; j + 8 <= rc; j += 8) {
                int2 e0 = sxy[rs + j + 0], e1 = sxy[rs + j + 1];
                int2 e2 = sxy[rs + j + 2], e3 = sxy[rs + j + 3];
                int2 e4 = sxy[rs + j + 4], e5 = sxy[rs + j + 5];
                int2 e6 = sxy[rs + j + 6], e7 = sxy[rs + j + 7];
                unsigned u0 = Y32[(size_t)(e0.x & COL_MASK) * 32 + fpair];
                unsigned u1 = Y32[(size_t)(e1.x & COL_MASK) * 32 + fpair];
                unsigned u2 = Y32[(size_t)(e2.x & COL_MASK) * 32 + fpair];
                unsigned u3 = Y32[(size_t)(e3.x & COL_MASK) * 32 + fpair];
                unsigned u4 = Y32[(size_t)(e4.x & COL_MASK) * 32 + fpair];
                unsigned u5 = Y32[(size_t)(e5.x & COL_MASK) * 32 + fpair];
                unsigned u6 = Y32[(size_t)(e6.x & COL_MASK) * 32 + fpair];
                unsigned u7 = Y32[(size_t)(e7.x & COL_MASK) * 32 + fpair];
                float v0 = __int_as_float(e0.y), v1 = __int_as_float(e1.y);
                float v2 = __int_as_float(e2.y), v3 = __int_as_float(e3.y);
                float v4 = __int_as_float(e4.y), v5 = __int_as_float(e5.y);
                float v6 = __int_as_float(e6.y), v7 = __int_as_float(e7.y);
                a0 = fmaf(v0, __uint_as_float(u0 << 16), a0);
                a1 = fmaf(v0, __uint_as_float(u0 & 0xFFFF0000u), a1);
                a0 = fmaf(v1, __uint_as_float(u1 << 16), a0);
                a1 = fmaf(v1, __uint_as_float(u1 & 0xFFFF0000u), a1);
                a0 = fmaf(v2, __uint_as_float(u2 << 16), a0);
                a1 = fmaf(v2, __uint_as_float(u2 & 0xFFFF0000u), a1);
                a0 = fmaf(v3, __uint_as_float(u3 << 16), a0);
                a1 = fmaf(v3, __uint_as_float(u3 & 0xFFFF0000u), a1);
                a0 = fmaf(v4, __uint_as_float(u4 << 16), a0);
                a1 = fmaf(v4, __uint_as_float(u4 & 0xFFFF0000u), a1);
                a0 = fmaf(v5, __uint_as_float(u5 << 16), a0);
                a1 = fmaf(v5, __uint_as_float(u5 & 0xFFFF0000u), a1);
                a0 = fmaf(v6, __uint_as_float(u6 << 16), a0);
                a1 = fmaf(v6, __uint_as_float(u6 & 0xFFFF0000u), a1);
                a0 = fmaf(v7, __uint_as_float(u7 << 16), a0);
                a1 = fmaf(v7, __uint_as_float(u7 & 0xFFFF0000u), a1);
            }
            for (; j + 2 <= rc; j += 2) {
                int2 e0 = sxy[rs + j + 0], e1 = sxy[rs + j + 1];
                unsigned u0 = Y32[(size_t)(e0.x & COL_MASK) * 32 + fpair];
                unsigned u1 = Y32[(size_t)(e1.x & COL_MASK) * 32 + fpair];
                float v0 = __int_as_float(e0.y), v1 = __int_as_float(e1.y);
                a0 = fmaf(v0, __uint_as_float(u0 << 16), a0);
                a1 = fmaf(v0, __uint_as_float(u0 & 0xFFFF0000u), a1);
                a0 = fmaf(v1, __uint_as_float(u1 << 16), a0);
                a1 = fmaf(v1, __uint_as_float(u1 & 0xFFFF0000u), a1);
            }
            if (j < rc) {
                int2 e0 = sxy[rs + j];
                unsigned u0 = Y32[(size_t)(e0.x & COL_MASK) * 32 + fpair];
                float v0 = __int_as_float(e0.y);
                a0 = fmaf(v0, __uint_as_float(u0 << 16), a0);
                a1 = fmaf(v0, __uint_as_float(u0 & 0xFFFF0000u), a1);
            }
            float2* op = (float2*)(out + (size_t)node * 64 + fpair * 2);
            float2 o = *op;
            o.x += a0; o.y += a1;
            *op = o;                                 // out holds Z
        }
        __syncthreads();
    }
}

// drains the (normally empty) overflow list with global atomics
__global__ __launch_bounds__(256) void overflow_scatter(
    const int* __restrict__ ovf_count, const int4* __restrict__ ovf,
    const unsigned short* __restrict__ Yb, float* __restrict__ out) {
    int cnt = min(*ovf_count, OVF_CAP);
    long long total = (long long)cnt * 64;
    for (long long i = blockIdx.x * 256 + threadIdx.x; i < total;
         i += (long long)gridDim.x * 256) {
        int e = (int)(i >> 6), f = (int)(i & 63);
        int4 a = ovf[e];
        atomicAdd(&out[(size_t)a.x * 64 + f],
                  __int_as_float(a.z) * bf2f(Yb[(size_t)a.y * 64 + f]));
    }
}

// ---------------- fallback (atomic path) ----------------

__global__ __launch_bounds__(256) void edge_scatter(
    const int* __restrict__ rows, const int* __restrict__ cols,
    const float* __restrict__ vals, const unsigned short* __restrict__ Yb,
    float* __restrict__ out, int n_edges)
{
    int t = blockIdx.x * 256 + threadIdx.x;
    int e = t >> 4;
    int f = (t & 15) << 2;
    if (e >= n_edges) return;
    int r = rows[e];
    int c = cols[e];
    float v = vals[e];
    const unsigned short* y = Yb + (size_t)c * 64 + f;
    float* o = out + (size_t)r * 64 + f;
    atomicAdd(o + 0, v * bf2f(y[0]));
    atomicAdd(o + 1, v * bf2f(y[1]));
    atomicAdd(o + 2, v * bf2f(y[2]));
    atomicAdd(o + 3, v * bf2f(y[3]));
}

extern "C" void kernel_launch(void* const* d_in, const int* in_sizes, int n_in,
                              void* d_out, int out_size, void* d_ws, size_t ws_size,
                              hipStream_t stream) {
    const int*   rows = (const int*)d_in[0];
    const int*   cols = (const int*)d_in[1];
    const float* vals = (const float*)d_in[2];
    const float* X    = (const float*)d_in[3];
    const float* W1   = (const float*)d_in[4];
    const float* b1   = (const float*)d_in[5];
    const float* W2   = (const float*)d_in[6];
    const float* b2   = (const float*)d_in[7];
    float* out = (float*)d_out;

    const int n_edges = in_sizes[0];
    const int n_nodes = in_sizes[3] / 64;
    const int nbuck = (n_nodes + ROWS_PER_BUCKET - 1) / ROWS_PER_BUCKET;

    char* ws = (char*)d_ws;
    size_t o_Yb     = 0;                                    // bf16 Y
    size_t o_packed = o_Yb + (size_t)n_nodes * 64 * 2;      // 16B-aligned (n*128)
    size_t o_ovf    = o_packed + (size_t)NBUCK_PAD * CAP * 8;
    size_t o_gcurs  = o_ovf + (size_t)OVF_CAP * 16;
    size_t o_ovfcnt = o_gcurs + NBUCK_PAD * 4;
    size_t need     = o_ovfcnt + 16;

    unsigned short* Yb = (unsigned short*)(ws + o_Yb);

    int nblocks = (n_nodes + 127) / 128;
    node_transform<<<nblocks, 256, 0, stream>>>(X, W1, b1, W2, b2, Yb, out, n_nodes);

    if (ws_size >= need && nbuck <= NBUCK_PAD && n_nodes <= (1 << COL_BITS)) {
        int2* packed  = (int2*)(ws + o_packed);
        int4* ovf     = (int4*)(ws + o_ovf);
        int*  gcursor = (int*)(ws + o_gcurs);
        int*  ovfcnt  = (int*)(ws + o_ovfcnt);

        int eb = (n_edges + CHUNK - 1) / CHUNK;

        cursor_init<<<(NBUCK_PAD + 255) / 256, 256, 0, stream>>>(gcursor, ovfcnt, NBUCK_PAD);
        bin_scatter<<<eb, 256, 0, stream>>>(rows, cols, vals, gcursor, packed,
                                            ovfcnt, ovf, n_edges);
        bucket_gather_rows<<<nbuck * 2, 256, 0, stream>>>(gcursor, packed, Yb, out, n_nodes);
        overflow_scatter<<<128, 256, 0, stream>>>(ovfcnt, ovf, Yb, out);
    } else {
        long long threads = (long long)n_edges * 16;
        int eblocks = (int)((threads + 255) / 256);
        edge_scatter<<<eblocks, 256, 0, stream>>>(rows, cols, vals, Yb, out, n_edges);
    }
}